// Round 1
// baseline (2372.077 us; speedup 1.0000x reference)
//
#include <hip/hip_runtime.h>

typedef _Float16 half2_t __attribute__((ext_vector_type(2)));
typedef _Float16 half8_t __attribute__((ext_vector_type(8)));

// ---------------- helpers ----------------

__device__ __forceinline__ float fdot2_(half2_t a, half2_t b, float c) {
#if __has_builtin(__builtin_amdgcn_fdot2)
  return __builtin_amdgcn_fdot2(a, b, c, false);
#else
  return fmaf((float)a[0], (float)b[0], fmaf((float)a[1], (float)b[1], c));
#endif
}

__device__ __forceinline__ void dot8_(float& acc, half8_t a, half8_t b) {
  half2_t a0 = {a[0], a[1]}, b0 = {b[0], b[1]};
  half2_t a1 = {a[2], a[3]}, b1 = {b[2], b[3]};
  half2_t a2 = {a[4], a[5]}, b2 = {b[4], b[5]};
  half2_t a3 = {a[6], a[7]}, b3 = {b[6], b[7]};
  acc = fdot2_(a0, b0, acc);
  acc = fdot2_(a1, b1, acc);
  acc = fdot2_(a2, b2, acc);
  acc = fdot2_(a3, b3, acc);
}

// XOR-swizzled LDS index helpers (units: _Float16 elements).
// XT logical [d=256][i=64]; 8-element blocks along i swizzled by (d>>3)&7.
__device__ __forceinline__ int xsw(int d, int i) {
  return (d << 6) + ((((i >> 3) ^ (d >> 3)) & 7) << 3) + (i & 7);
}
__device__ __forceinline__ int xsw8(int d, int o) {  // i = o*8, aligned block
  return (d << 6) + (((o ^ (d >> 3)) & 7) << 3);
}
// PT logical [j=64][i=64]; blocks along i swizzled by j&7.
__device__ __forceinline__ int psw(int j, int i) {
  return (j << 6) + ((((i >> 3) ^ j) & 7) << 3) + (i & 7);
}
__device__ __forceinline__ int psw8(int j, int o) {
  return (j << 6) + (((o ^ j) & 7) << 3);
}
// G logical [f=256][dd=64]; blocks along dd swizzled by (f>>3)&7.
__device__ __forceinline__ int gsw8(int f, int o) {
  return (f << 6) + (((o ^ (f >> 3)) & 7) << 3);
}

// ---------------- K0: h = mean_t x ----------------
__global__ void k_hmean(const float* __restrict__ x, float* __restrict__ h) {
  int bc = blockIdx.x;          // b*64+c, 1024 blocks
  int d = threadIdx.x;          // 256
  const float* xp = x + (size_t)bc * (128 * 256) + d;
  float s = 0.f;
  #pragma unroll 8
  for (int t = 0; t < 128; ++t) s += xp[(size_t)t * 256];
  h[bc * 256 + d] = s * (1.f / 128.f);
}

// ---------------- K1: q = h@wq^T, k = h@wk^T ----------------
__global__ void k_qk(const float* __restrict__ h, const float* __restrict__ wq,
                     const float* __restrict__ wk, float* __restrict__ q,
                     float* __restrict__ k) {
  int gid = blockIdx.x * 256 + threadIdx.x;  // 65536 total
  int isK = gid >> 15;
  int e = gid & 32767;       // (b*64+i)*32 + kk
  int kk = e & 31;
  int bi = e >> 5;
  const float4* h4 = (const float4*)(h + bi * 256);
  const float4* w4 = (const float4*)((isK ? wk : wq) + kk * 256);
  float s = 0.f;
  #pragma unroll 4
  for (int d = 0; d < 64; ++d) {
    float4 a = h4[d], bv = w4[d];
    s = fmaf(a.x, bv.x, s); s = fmaf(a.y, bv.y, s);
    s = fmaf(a.z, bv.z, s); s = fmaf(a.w, bv.w, s);
  }
  (isK ? k : q)[e] = s;
}

// ---------------- K2: sim -> tanh -> delta_a out, top-8 -> column masks ----------------
__global__ void k_adj(const float* __restrict__ q, const float* __restrict__ k,
                      const float* __restrict__ sadj, float* __restrict__ dout,
                      unsigned long long* __restrict__ cmask) {
  __shared__ float qs[64][33], ks[64][33];
  __shared__ float ad[64][65];
  __shared__ unsigned long long rowm[64];
  int b = blockIdx.x, tid = threadIdx.x;   // 16 blocks x 256
  for (int r = 0; r < 8; ++r) {
    int idx = r * 256 + tid;
    qs[idx >> 5][idx & 31] = q[b * 2048 + idx];
    ks[idx >> 5][idx & 31] = k[b * 2048 + idx];
  }
  __syncthreads();
  const float rs = 0.17677669529663687f;  // 1/sqrt(32)
  for (int r = 0; r < 16; ++r) {
    int idx = r * 256 + tid;
    int i = idx >> 6, j = idx & 63;
    float s = 0.f;
    #pragma unroll 8
    for (int kk = 0; kk < 32; ++kk) s = fmaf(qs[i][kk], ks[j][kk], s);
    float dv = tanhf(s * rs);
    dout[b * 4096 + idx] = dv;      // delta_a output (fp32)
    ad[i][j] = sadj[idx] + dv;      // adaptive
  }
  __syncthreads();
  if (tid < 64) {
    // top-8 of |adaptive[row tid]|, ties -> smallest index (matches lax.top_k)
    unsigned long long sel = 0ull;
    for (int p = 0; p < 8; ++p) {
      float best = -1.f; int bj = 0;
      for (int j = 0; j < 64; ++j) {
        if ((sel >> j) & 1ull) continue;
        float v = fabsf(ad[tid][j]);
        if (v > best) { best = v; bj = j; }
      }
      sel |= 1ull << bj;
    }
    rowm[tid] = sel;
  }
  __syncthreads();
  if (tid < 64) {
    // column mask for target j=tid: allowed sources i (plus self loop)
    unsigned long long cmv = 1ull << tid;
    for (int i = 0; i < 64; ++i) cmv |= ((rowm[i] >> tid) & 1ull) << i;
    cmask[b * 64 + tid] = cmv;
  }
}

// ---------------- K3: vs[h,:] = att_src[h]·gat_lin_h, vd likewise ----------------
__global__ void k_vsd(const float* __restrict__ glin, const float* __restrict__ asrc,
                      const float* __restrict__ adst, float* __restrict__ vs,
                      float* __restrict__ vd) {
  int hh = blockIdx.x, d = threadIdx.x;  // 8 x 256
  const float* gb = glin + (size_t)hh * 256 * 256;
  float s = 0.f, t = 0.f;
  for (int f = 0; f < 256; ++f) {
    float g = gb[f * 256 + d];
    s = fmaf(asrc[hh * 256 + f], g, s);
    t = fmaf(adst[hh * 256 + f], g, t);
  }
  vs[hh * 256 + d] = s;
  vd[hh * 256 + d] = t;
}

// ---------------- K4: cast gat_lin to f16 ----------------
__global__ void k_cast(const float* __restrict__ g, _Float16* __restrict__ o) {
  int i = (blockIdx.x * 256 + threadIdx.x) * 8;  // 256 blocks
  float4 a = *(const float4*)(g + i);
  float4 b = *(const float4*)(g + i + 4);
  half8_t v;
  v[0] = (_Float16)a.x; v[1] = (_Float16)a.y; v[2] = (_Float16)a.z; v[3] = (_Float16)a.w;
  v[4] = (_Float16)b.x; v[5] = (_Float16)b.y; v[6] = (_Float16)b.z; v[7] = (_Float16)b.w;
  *(half8_t*)(o + i) = v;
}

// ---------------- K5: main fused GAT per (b,t) ----------------
__global__ __launch_bounds__(256, 1) void k_main(
    const float* __restrict__ x, const float* __restrict__ vs,
    const float* __restrict__ vd, const unsigned long long* __restrict__ cmask,
    const _Float16* __restrict__ g16, const float* __restrict__ bias,
    float* __restrict__ out)
{
  __shared__ __align__(16) _Float16 XT[16384];    // x tile, [d][i] swizzled
  __shared__ __align__(16) _Float16 PT[4096];     // alpha^T, [j][i] swizzled
  __shared__ __align__(16) _Float16 XG[64 * 264]; // xagg [j][d], stride 264
  __shared__ __align__(16) _Float16 G[16384];     // gat_lin chunk [f][dd] swizzled
  __shared__ __align__(16) float VSD[4096];       // vs rows 0..7, vd rows 8..15
  __shared__ float AS[512];                       // [h][i]
  __shared__ float AD[512];                       // [h][j]
  __shared__ float RD[256];
  __shared__ float RD2[256];

  const int tid = threadIdx.x;
  const int bt = blockIdx.x;
  const int b = bt >> 7;
  const int t = bt & 127;

  // stage VSD
  #pragma unroll
  for (int r = 0; r < 4; ++r) {
    int i4 = r * 256 + tid;
    float4 v;
    if (i4 < 512) v = *(const float4*)(vs + i4 * 4);
    else          v = *(const float4*)(vd + (i4 - 512) * 4);
    *(float4*)&VSD[i4 * 4] = v;
  }

  // load X[b,:,t,:] -> XT (f16, transposed, swizzled)
  {
    int iq = tid >> 6;
    int fq = tid & 63;
    #pragma unroll
    for (int r = 0; r < 16; ++r) {
      int i = r * 4 + iq;
      int d0 = fq * 4;
      const float* xp = x + (((size_t)(b * 64 + i) * 128 + t) << 8) + d0;
      float4 v = *(const float4*)xp;
      XT[xsw(d0 + 0, i)] = (_Float16)v.x;
      XT[xsw(d0 + 1, i)] = (_Float16)v.y;
      XT[xsw(d0 + 2, i)] = (_Float16)v.z;
      XT[xsw(d0 + 3, i)] = (_Float16)v.w;
    }
  }
  __syncthreads();

  // scores: a_s[i,h], a_d[i,h] fp32
  {
    int i = tid & 63, hh = tid >> 6;
    const float* pa = &VSD[hh * 256];
    const float* pb = &VSD[(hh + 4) * 256];
    const float* pc = &VSD[2048 + hh * 256];
    const float* pd = &VSD[2048 + (hh + 4) * 256];
    float a0 = 0, a1 = 0, a2 = 0, a3 = 0;
    for (int d = 0; d < 256; ++d) {
      float xv = (float)XT[xsw(d, i)];
      a0 = fmaf(xv, pa[d], a0);
      a1 = fmaf(xv, pb[d], a1);
      a2 = fmaf(xv, pc[d], a2);
      a3 = fmaf(xv, pd[d], a3);
    }
    AS[hh * 64 + i] = a0; AS[(hh + 4) * 64 + i] = a1;
    AD[hh * 64 + i] = a2; AD[(hh + 4) * 64 + i] = a3;
  }

  float acc[8][8];
  #pragma unroll
  for (int jj = 0; jj < 8; ++jj)
    #pragma unroll
    for (int ff = 0; ff < 8; ++ff) acc[jj][ff] = 0.f;

  const unsigned long long cm = cmask[b * 64 + (tid & 63)];
  const int jg = tid >> 5, sg = tid & 31;
  __syncthreads();

  for (int h = 0; h < 8; ++h) {
    // masked softmax over sources i, per target j -> PT (f16, normalized)
    {
      int j = tid & 63, qd = tid >> 6;
      float adj = AD[h * 64 + j];
      float ev[16];
      float m = -1e30f;
      #pragma unroll
      for (int ii = 0; ii < 16; ++ii) {
        int i = qd * 16 + ii;
        float e = AS[h * 64 + i] + adj;
        e = fmaxf(e, 0.f) + 0.2f * fminf(e, 0.f);   // leaky_relu(0.2)
        e = ((cm >> i) & 1ULL) ? e : -1e30f;        // mask
        ev[ii] = e;
        m = fmaxf(m, e);
      }
      RD[qd * 64 + j] = m;
      __syncthreads();
      m = fmaxf(fmaxf(RD[j], RD[64 + j]), fmaxf(RD[128 + j], RD[192 + j]));
      float s = 0.f;
      #pragma unroll
      for (int ii = 0; ii < 16; ++ii) {
        float p = __expf(ev[ii] - m);               // masked -> exp(-huge)=0
        ev[ii] = p;
        s += p;
      }
      RD2[qd * 64 + j] = s;
      __syncthreads();
      s = (RD2[j] + RD2[64 + j]) + (RD2[128 + j] + RD2[192 + j]);
      float rinv = 1.f / s;
      #pragma unroll
      for (int ii = 0; ii < 16; ++ii)
        PT[psw(j, qd * 16 + ii)] = (_Float16)(ev[ii] * rinv);
    }
    __syncthreads();

    // GEMM1: XG[j][d] = sum_i PT[j][i] * XT[d][i]
    {
      float xacc[8][8];
      #pragma unroll
      for (int jj = 0; jj < 8; ++jj)
        #pragma unroll
        for (int kk = 0; kk < 8; ++kk) xacc[jj][kk] = 0.f;
      for (int o = 0; o < 8; ++o) {
        half8_t pt[8];
        #pragma unroll
        for (int jj = 0; jj < 8; ++jj)
          pt[jj] = *(const half8_t*)&PT[psw8(jg * 8 + jj, o)];
        #pragma unroll
        for (int kk = 0; kk < 8; ++kk) {
          half8_t xt = *(const half8_t*)&XT[xsw8(sg * 8 + kk, o)];
          #pragma unroll
          for (int jj = 0; jj < 8; ++jj) dot8_(xacc[jj][kk], pt[jj], xt);
        }
      }
      #pragma unroll
      for (int jj = 0; jj < 8; ++jj) {
        half8_t w;
        #pragma unroll
        for (int kk = 0; kk < 8; ++kk) w[kk] = (_Float16)xacc[jj][kk];
        *(half8_t*)&XG[(jg * 8 + jj) * 264 + sg * 8] = w;
      }
    }

    // GEMM2: acc[j][f] += sum_d XG[j][d] * gat_lin_h[f][d], d chunked by 64
    for (int dc = 0; dc < 4; ++dc) {
      // stage G chunk (f = tid row, 64 d's)
      {
        const _Float16* gp = g16 + ((size_t)(h * 256 + tid) << 8) + dc * 64;
        #pragma unroll
        for (int ob = 0; ob < 8; ++ob) {
          half8_t gv = *(const half8_t*)(gp + ob * 8);
          *(half8_t*)&G[gsw8(tid, ob)] = gv;
        }
      }
      __syncthreads();  // G ready (and XG, for dc==0)
      #pragma unroll
      for (int w8 = 0; w8 < 8; ++w8) {
        half8_t xa[8];
        #pragma unroll
        for (int jj = 0; jj < 8; ++jj)
          xa[jj] = *(const half8_t*)&XG[(jg * 8 + jj) * 264 + dc * 64 + w8 * 8];
        #pragma unroll
        for (int ff = 0; ff < 8; ++ff) {
          half8_t gg = *(const half8_t*)&G[gsw8(sg * 8 + ff, w8)];
          #pragma unroll
          for (int jj = 0; jj < 8; ++jj) dot8_(acc[jj][ff], xa[jj], gg);
        }
      }
      __syncthreads();  // done with G before next stage overwrites
    }
  }

  // epilogue: out[b, j, t, f] = acc/8 + bias[f]
  {
    float bv[8];
    #pragma unroll
    for (int ff = 0; ff < 8; ++ff) bv[ff] = bias[sg * 8 + ff];
    #pragma unroll
    for (int jj = 0; jj < 8; ++jj) {
      int j = jg * 8 + jj;
      float* op = out + (((size_t)(b * 64 + j) * 128 + t) << 8) + sg * 8;
      float4 v0, v1;
      v0.x = fmaf(acc[jj][0], 0.125f, bv[0]);
      v0.y = fmaf(acc[jj][1], 0.125f, bv[1]);
      v0.z = fmaf(acc[jj][2], 0.125f, bv[2]);
      v0.w = fmaf(acc[jj][3], 0.125f, bv[3]);
      v1.x = fmaf(acc[jj][4], 0.125f, bv[4]);
      v1.y = fmaf(acc[jj][5], 0.125f, bv[5]);
      v1.z = fmaf(acc[jj][6], 0.125f, bv[6]);
      v1.w = fmaf(acc[jj][7], 0.125f, bv[7]);
      *(float4*)op = v0;
      *(float4*)(op + 4) = v1;
    }
  }
}

// ---------------- launch ----------------
extern "C" void kernel_launch(void* const* d_in, const int* in_sizes, int n_in,
                              void* d_out, int out_size, void* d_ws, size_t ws_size,
                              hipStream_t stream) {
  const float* x    = (const float*)d_in[0];
  const float* sadj = (const float*)d_in[1];
  const float* wq   = (const float*)d_in[2];
  const float* wk   = (const float*)d_in[3];
  const float* glin = (const float*)d_in[4];
  const float* asrc = (const float*)d_in[5];
  const float* adst = (const float*)d_in[6];
  const float* bias = (const float*)d_in[7];

  float* out = (float*)d_out;
  float* delta_out = out + (size_t)16 * 64 * 128 * 256;  // 33554432

  char* ws = (char*)d_ws;
  float* h  = (float*)(ws + 0);                 // 262144 f32
  float* q  = (float*)(ws + 1048576);           // 32768 f32
  float* k  = (float*)(ws + 1179648);           // 32768 f32
  float* vs = (float*)(ws + 1310720);           // 2048 f32
  float* vd = (float*)(ws + 1318912);           // 2048 f32
  unsigned long long* cm = (unsigned long long*)(ws + 1327104);  // 1024 u64
  _Float16* g16 = (_Float16*)(ws + 1335296);    // 524288 f16

  hipLaunchKernelGGL(k_hmean, dim3(1024), dim3(256), 0, stream, x, h);
  hipLaunchKernelGGL(k_qk,    dim3(256),  dim3(256), 0, stream, h, wq, wk, q, k);
  hipLaunchKernelGGL(k_adj,   dim3(16),   dim3(256), 0, stream, q, k, sadj, delta_out, cm);
  hipLaunchKernelGGL(k_vsd,   dim3(8),    dim3(256), 0, stream, glin, asrc, adst, vs, vd);
  hipLaunchKernelGGL(k_cast,  dim3(256),  dim3(256), 0, stream, glin, g16);
  hipLaunchKernelGGL(k_main,  dim3(2048), dim3(256), 0, stream, x, vs, vd, cm, g16, bias, out);
}

// Round 3
// 373.389 us; speedup vs baseline: 6.3528x; 6.3528x over previous
//
#include <hip/hip_runtime.h>

typedef _Float16 h2_t __attribute__((ext_vector_type(2)));
typedef _Float16 h4_t __attribute__((ext_vector_type(4)));
typedef _Float16 h8_t __attribute__((ext_vector_type(8)));
typedef __fp16 fp16x2 __attribute__((ext_vector_type(2)));
typedef float f32x16 __attribute__((ext_vector_type(16)));

// ---------------- helpers ----------------

__device__ __forceinline__ h2_t pkrtz(float a, float b) {
  union { fp16x2 f; h2_t h; } u;
  u.f = __builtin_amdgcn_cvt_pkrtz(a, b);
  return u.h;
}

__device__ __forceinline__ float fdot2_(h2_t a, h2_t b, float c) {
#if __has_builtin(__builtin_amdgcn_fdot2)
  return __builtin_amdgcn_fdot2(a, b, c, false);
#else
  return fmaf((float)a[0], (float)b[0], fmaf((float)a[1], (float)b[1], c));
#endif
}

__device__ __forceinline__ h2_t u2h(unsigned u) {
  union { unsigned u; h2_t h; } x; x.u = u; return x.h;
}

__device__ __forceinline__ void gload16(const void* g, void* l) {
  __builtin_amdgcn_global_load_lds(
      (const __attribute__((address_space(1))) void*)g,
      (__attribute__((address_space(3))) void*)l, 16, 0, 0);
}

// ---------------- K0: h = mean_t x ----------------
__global__ void k_hmean(const float* __restrict__ x, float* __restrict__ h) {
  int bc = blockIdx.x;          // b*64+c, 1024 blocks
  int d = threadIdx.x;          // 256
  const float* xp = x + (size_t)bc * (128 * 256) + d;
  float s = 0.f;
  #pragma unroll 8
  for (int t = 0; t < 128; ++t) s += xp[(size_t)t * 256];
  h[bc * 256 + d] = s * (1.f / 128.f);
}

// ---------------- K1: q = h@wq^T, k = h@wk^T ----------------
__global__ void k_qk(const float* __restrict__ h, const float* __restrict__ wq,
                     const float* __restrict__ wk, float* __restrict__ q,
                     float* __restrict__ k) {
  int gid = blockIdx.x * 256 + threadIdx.x;  // 65536 total
  int isK = gid >> 15;
  int e = gid & 32767;       // (b*64+i)*32 + kk
  int kk = e & 31;
  int bi = e >> 5;
  const float4* h4 = (const float4*)(h + bi * 256);
  const float4* w4 = (const float4*)((isK ? wk : wq) + kk * 256);
  float s = 0.f;
  #pragma unroll 4
  for (int d = 0; d < 64; ++d) {
    float4 a = h4[d], bv = w4[d];
    s = fmaf(a.x, bv.x, s); s = fmaf(a.y, bv.y, s);
    s = fmaf(a.z, bv.z, s); s = fmaf(a.w, bv.w, s);
  }
  (isK ? k : q)[e] = s;
}

// ---------------- K2: sim -> tanh -> delta_a out, top-8 -> column masks ----------------
__global__ void k_adj(const float* __restrict__ q, const float* __restrict__ k,
                      const float* __restrict__ sadj, float* __restrict__ dout,
                      unsigned long long* __restrict__ cmask) {
  __shared__ float qs[64][33], ks[64][33];
  __shared__ float ad[64][65];
  __shared__ unsigned long long rowm[64];
  int b = blockIdx.x, tid = threadIdx.x;   // 16 blocks x 256
  for (int r = 0; r < 8; ++r) {
    int idx = r * 256 + tid;
    qs[idx >> 5][idx & 31] = q[b * 2048 + idx];
    ks[idx >> 5][idx & 31] = k[b * 2048 + idx];
  }
  __syncthreads();
  const float rs = 0.17677669529663687f;  // 1/sqrt(32)
  for (int r = 0; r < 16; ++r) {
    int idx = r * 256 + tid;
    int i = idx >> 6, j = idx & 63;
    float s = 0.f;
    #pragma unroll 8
    for (int kk = 0; kk < 32; ++kk) s = fmaf(qs[i][kk], ks[j][kk], s);
    float dv = tanhf(s * rs);
    dout[b * 4096 + idx] = dv;      // delta_a output (fp32)
    ad[i][j] = sadj[idx] + dv;      // adaptive
  }
  __syncthreads();
  if (tid < 64) {
    unsigned long long sel = 0ull;
    for (int p = 0; p < 8; ++p) {
      float best = -1.f; int bj = 0;
      for (int j = 0; j < 64; ++j) {
        if ((sel >> j) & 1ull) continue;
        float v = fabsf(ad[tid][j]);
        if (v > best) { best = v; bj = j; }
      }
      sel |= 1ull << bj;
    }
    rowm[tid] = sel;
  }
  __syncthreads();
  if (tid < 64) {
    unsigned long long cmv = 1ull << tid;   // self loop
    for (int i = 0; i < 64; ++i) cmv |= ((rowm[i] >> tid) & 1ull) << i;
    cmask[b * 64 + tid] = cmv;
  }
}

// ---------------- K3: vsd16[h]=att_src[h].G_h (rows 0-7), att_dst (rows 8-15), f16 ----------------
__global__ void k_vsd(const float* __restrict__ glin, const float* __restrict__ asrc,
                      const float* __restrict__ adst, _Float16* __restrict__ vsd16) {
  int hh = blockIdx.x, d = threadIdx.x;  // 8 x 256
  const float* gb = glin + (size_t)hh * 65536;
  float s = 0.f, t = 0.f;
  for (int f = 0; f < 256; ++f) {
    float g = gb[f * 256 + d];
    s = fmaf(asrc[hh * 256 + f], g, s);
    t = fmaf(adst[hh * 256 + f], g, t);
  }
  vsd16[hh * 256 + d] = (_Float16)s;
  vsd16[(8 + hh) * 256 + d] = (_Float16)t;
}

// ---------------- K4: cast + pre-swizzle gat_lin for direct global_load_lds staging ----------------
// g16s layout: [sc = h*4+dc][f:256][slot:8][e:8] f16 ; element = G[h*256+f][dc*64 + ((slot^(f&7))&7)*8 + e]
__global__ void k_gswz(const float* __restrict__ g, _Float16* __restrict__ o) {
  int gid = blockIdx.x * 256 + threadIdx.x;   // 65536 (each writes 8 f16)
  int s = gid & 7;
  int f = (gid >> 3) & 255;
  int sc = gid >> 11;          // h*4+dc
  int h = sc >> 2, dc = sc & 3;
  const float* src = g + ((size_t)(h * 256 + f) << 8) + dc * 64 + (((s ^ (f & 7)) & 7) << 3);
  float4 a = *(const float4*)src;
  float4 bq = *(const float4*)(src + 4);
  h8_t v;
  v[0] = (_Float16)a.x;  v[1] = (_Float16)a.y;  v[2] = (_Float16)a.z;  v[3] = (_Float16)a.w;
  v[4] = (_Float16)bq.x; v[5] = (_Float16)bq.y; v[6] = (_Float16)bq.z; v[7] = (_Float16)bq.w;
  *(h8_t*)(o + (size_t)gid * 8) = v;
}

// ---------------- K5: main fused GAT per (b,t), MFMA 32x32x16 f16 ----------------
// 512 threads = 8 waves. wave w: mg=w&1 (i-half, GEMM-A M tile), fg=w>>1 (f-quarter 64).
// LDS map (bytes):
//   XR   @0      : 32768  X[i=64][d=256] f16, row 512B, slot16 = (db&24)|((db^(i&7))&7)
//   GB   @32768  : 65536  2 x 32KB G chunk [f=256][slot:8][8] (linear from pre-swizzled global)
//   WXT  @98304  : 32768  WX^T [f=256][i=64] f16, row 128B, slot = ((i>>3)^(f&7))&7
//   PT   @131072 : 8192   alpha^T [j=64][i=64] f16, row 128B, same swizzle
//   AS   @139264 : 2048   a_src[h=8][i=64] f32
//   AD   @141312 : 2048   a_dst[h=8][j=64] f32
__global__ __launch_bounds__(512) void k_main(
    const float* __restrict__ x, const _Float16* __restrict__ vsd16,
    const unsigned long long* __restrict__ cmask,
    const _Float16* __restrict__ g16s, const float* __restrict__ bias,
    float* __restrict__ out)
{
  __shared__ __align__(16) char LDS[143360];
  char* XR  = LDS;
  char* GB  = LDS + 32768;
  char* WXT = LDS + 98304;
  char* PT  = LDS + 131072;
  float* AS = (float*)(LDS + 139264);
  float* AD = (float*)(LDS + 141312);

  const int tid = threadIdx.x;
  const int lane = tid & 63;
  const int w = __builtin_amdgcn_readfirstlane(tid >> 6);
  const int hi = lane >> 5;
  const int l5 = lane & 31;
  const int l7 = lane & 7;
  const int mg = w & 1;
  const int fg = w >> 1;
  const int bt = blockIdx.x;
  const int b = bt >> 7, t = bt & 127;

  // early per-lane loads
  const int jj = w * 8 + (lane >> 3);               // softmax target row
  const unsigned long long cm = cmask[b * 64 + jj];
  const int fb0 = l5 + fg * 64, fb1 = fb0 + 32;
  const float bi0 = bias[fb0], bi1 = bias[fb1];

  // issue G chunk 0 into buffer 0 (overlaps X staging)
  {
    const char* gs = (const char*)g16s + (size_t)w * 4096 + (size_t)lane * 16;
    char* ld = GB + w * 4096;
    #pragma unroll
    for (int q = 0; q < 4; ++q) gload16(gs + q * 1024, ld + q * 1024);
  }

  // stage X[b,:,t,:] -> XR f16 swizzled. wave w: rows w*8..w*8+7, lane covers d=lane*4..+3
  #pragma unroll
  for (int r = 0; r < 8; ++r) {
    int i = w * 8 + r;
    const float4 v = *(const float4*)(x + (((size_t)(b * 64 + i) * 128 + t) << 8) + lane * 4);
    h2_t p0 = pkrtz(v.x, v.y);
    h2_t p1 = pkrtz(v.z, v.w);
    h4_t hv; hv[0] = p0[0]; hv[1] = p0[1]; hv[2] = p1[0]; hv[3] = p1[1];
    int db = lane >> 1;
    int off = i * 512 + (((db & 24) | ((db ^ (i & 7)) & 7)) << 4) + ((lane & 1) << 3);
    *(h4_t*)(XR + off) = hv;
  }
  asm volatile("s_waitcnt vmcnt(0)" ::: "memory");
  asm volatile("s_waitcnt lgkmcnt(0)" ::: "memory");
  __builtin_amdgcn_s_barrier();      // XR ready everywhere

  // A-fragments (X) -- head-invariant, keep in registers: 16 k-steps x 4 VGPR
  h8_t Af[16];
  {
    int i = mg * 32 + l5;
    #pragma unroll
    for (int k = 0; k < 16; ++k) {
      int db = k * 2 + hi;
      Af[k] = *(const h8_t*)(XR + i * 512 + (((db & 24) | ((db ^ l7) & 7)) << 4));
    }
  }

  // scores: thread (h = w, i = lane): a_s, a_d via f16 dot2
  {
    float a_s = 0.f, a_d = 0.f;
    const unsigned* vsp = (const unsigned*)vsd16 + w * 128;
    const unsigned* vdp = (const unsigned*)vsd16 + (8 + w) * 128;
    #pragma unroll 4
    for (int db = 0; db < 32; ++db) {
      h8_t xv = *(const h8_t*)(XR + lane * 512 + (((db & 24) | ((db ^ l7) & 7)) << 4));
      #pragma unroll
      for (int c = 0; c < 4; ++c) {
        h2_t x2; x2[0] = xv[c * 2]; x2[1] = xv[c * 2 + 1];
        a_s = fdot2_(x2, u2h(vsp[db * 4 + c]), a_s);
        a_d = fdot2_(x2, u2h(vdp[db * 4 + c]), a_d);
      }
    }
    AS[w * 64 + lane] = a_s;
    AD[w * 64 + lane] = a_d;
  }
  asm volatile("s_waitcnt lgkmcnt(0)" ::: "memory");
  __builtin_amdgcn_s_barrier();      // AS/AD ready

  f32x16 acc00 = {}, acc01 = {}, acc10 = {}, acc11 = {};

  #pragma unroll 1
  for (int h = 0; h < 8; ++h) {
    f32x16 d0 = {}, d1 = {};
    #pragma unroll
    for (int dc = 0; dc < 4; ++dc) {
      const int s = h * 4 + dc;
      asm volatile("s_waitcnt lgkmcnt(0)" ::: "memory");
      __builtin_amdgcn_s_barrier();                 // [A] all waves done with buf (s+1)&1
      if (s < 31) {
        const char* gs = (const char*)g16s + (size_t)(s + 1) * 32768 + (size_t)w * 4096 + (size_t)lane * 16;
        char* ld = GB + ((s + 1) & 1) * 32768 + w * 4096;
        #pragma unroll
        for (int q = 0; q < 4; ++q) gload16(gs + q * 1024, ld + q * 1024);
        asm volatile("s_waitcnt vmcnt(4)" ::: "memory");  // chunk s resident (mine)
      } else {
        asm volatile("s_waitcnt vmcnt(0)" ::: "memory");
      }
      __builtin_amdgcn_s_barrier();                 // [D] chunk s resident everywhere

      if (dc == 0) {
        // masked softmax for head h (wave-local: 8 j per wave, 8 lanes per j)
        const int ip = lane & 7;
        float ad_j = AD[h * 64 + jj];
        float ev[8], m = -1e30f;
        #pragma unroll
        for (int c = 0; c < 8; ++c) {
          int i = ip * 8 + c;
          float e = AS[h * 64 + i] + ad_j;
          e = (e > 0.f) ? e : 0.2f * e;             // leaky_relu(0.2)
          e = ((cm >> i) & 1ULL) ? e : -1e30f;      // mask
          ev[c] = e; m = fmaxf(m, e);
        }
        m = fmaxf(m, __shfl_xor(m, 1));
        m = fmaxf(m, __shfl_xor(m, 2));
        m = fmaxf(m, __shfl_xor(m, 4));
        float ss = 0.f;
        #pragma unroll
        for (int c = 0; c < 8; ++c) { ev[c] = __expf(ev[c] - m); ss += ev[c]; }
        ss += __shfl_xor(ss, 1); ss += __shfl_xor(ss, 2); ss += __shfl_xor(ss, 4);
        float rinv = 1.f / ss;
        h8_t pv;
        #pragma unroll
        for (int c = 0; c < 4; ++c) {
          h2_t p = pkrtz(ev[2 * c] * rinv, ev[2 * c + 1] * rinv);
          pv[2 * c] = p[0]; pv[2 * c + 1] = p[1];
        }
        *(h8_t*)(PT + jj * 128 + (((ip ^ (jj & 7)) & 7) << 4)) = pv;
      }

      // GEMM-A quarter: WX += X[:,d-chunk] * G[:,d-chunk]^T
      const char* gb = GB + (s & 1) * 32768;
      #pragma unroll
      for (int kk = 0; kk < 4; ++kk) {
        int sl = (((kk * 2 + hi) ^ l7) & 7) << 4;
        h8_t b0 = *(const h8_t*)(gb + fb0 * 128 + sl);
        h8_t b1 = *(const h8_t*)(gb + fb1 * 128 + sl);
        d0 = __builtin_amdgcn_mfma_f32_32x32x16_f16(Af[dc * 4 + kk], b0, d0, 0, 0, 0);
        d1 = __builtin_amdgcn_mfma_f32_32x32x16_f16(Af[dc * 4 + kk], b1, d1, 0, 0, 0);
      }
    } // dc

    // transposed f16 store of WX -> WXT (b64-packed, wave-pair shares f rows, disjoint i)
    #pragma unroll
    for (int rq = 0; rq < 4; ++rq) {
      int db = mg * 4 + rq;
      int sl = ((db ^ l7) & 7) << 4;
      h2_t a0 = pkrtz(d0[rq * 4 + 0], d0[rq * 4 + 1]);
      h2_t a1 = pkrtz(d0[rq * 4 + 2], d0[rq * 4 + 3]);
      h4_t v0; v0[0] = a0[0]; v0[1] = a0[1]; v0[2] = a1[0]; v0[3] = a1[1];
      *(h4_t*)(WXT + fb0 * 128 + sl + hi * 8) = v0;
      h2_t b0p = pkrtz(d1[rq * 4 + 0], d1[rq * 4 + 1]);
      h2_t b1p = pkrtz(d1[rq * 4 + 2], d1[rq * 4 + 3]);
      h4_t v1; v1[0] = b0p[0]; v1[1] = b0p[1]; v1[2] = b1p[0]; v1[3] = b1p[1];
      *(h4_t*)(WXT + fb1 * 128 + sl + hi * 8) = v1;
    }
    asm volatile("s_waitcnt lgkmcnt(0)" ::: "memory");
    __builtin_amdgcn_s_barrier();     // WXT visible to wave-pair partner

    // GEMM-B: OUT += P^T * WX   (A = PT rows j, B = WXT rows f, K = i = 64)
    #pragma unroll
    for (int kb = 0; kb < 4; ++kb) {
      int sl = (((kb * 2 + hi) ^ l7) & 7) << 4;
      h8_t pa0 = *(const h8_t*)(PT + l5 * 128 + sl);
      h8_t pa1 = *(const h8_t*)(PT + (l5 + 32) * 128 + sl);
      h8_t wb0 = *(const h8_t*)(WXT + fb0 * 128 + sl);
      h8_t wb1 = *(const h8_t*)(WXT + fb1 * 128 + sl);
      acc00 = __builtin_amdgcn_mfma_f32_32x32x16_f16(pa0, wb0, acc00, 0, 0, 0);
      acc01 = __builtin_amdgcn_mfma_f32_32x32x16_f16(pa0, wb1, acc01, 0, 0, 0);
      acc10 = __builtin_amdgcn_mfma_f32_32x32x16_f16(pa1, wb0, acc10, 0, 0, 0);
      acc11 = __builtin_amdgcn_mfma_f32_32x32x16_f16(pa1, wb1, acc11, 0, 0, 0);
    }
  } // h

  // epilogue: out[b, j, t, f] = acc/8 + bias[f]
  float* ob = out + ((size_t)(b * 64) * 128 + t) * 256;
  #pragma unroll
  for (int rq = 0; rq < 4; ++rq) {
    #pragma unroll
    for (int rr = 0; rr < 4; ++rr) {
      int r = rq * 4 + rr;
      int j0 = 8 * rq + 4 * hi + rr;
      ob[(size_t)j0 * 32768 + fb0]        = acc00[r] * 0.125f + bi0;
      ob[(size_t)j0 * 32768 + fb1]        = acc01[r] * 0.125f + bi1;
      ob[(size_t)(j0 + 32) * 32768 + fb0] = acc10[r] * 0.125f + bi0;
      ob[(size_t)(j0 + 32) * 32768 + fb1] = acc11[r] * 0.125f + bi1;
    }
  }
}

// ---------------- launch ----------------
extern "C" void kernel_launch(void* const* d_in, const int* in_sizes, int n_in,
                              void* d_out, int out_size, void* d_ws, size_t ws_size,
                              hipStream_t stream) {
  const float* x    = (const float*)d_in[0];
  const float* sadj = (const float*)d_in[1];
  const float* wq   = (const float*)d_in[2];
  const float* wk   = (const float*)d_in[3];
  const float* glin = (const float*)d_in[4];
  const float* asrc = (const float*)d_in[5];
  const float* adst = (const float*)d_in[6];
  const float* bias = (const float*)d_in[7];

  float* out = (float*)d_out;
  float* delta_out = out + (size_t)16 * 64 * 128 * 256;  // 33554432

  char* ws = (char*)d_ws;
  float* h   = (float*)(ws + 0);                  // 1048576 B
  float* q   = (float*)(ws + 1048576);            // 131072 B
  float* k   = (float*)(ws + 1179648);            // 131072 B
  unsigned long long* cm = (unsigned long long*)(ws + 1310720);  // 8192 B
  _Float16* vsd16 = (_Float16*)(ws + 1318912);    // 8192 B
  _Float16* g16s  = (_Float16*)(ws + 1327104);    // 1048576 B

  hipLaunchKernelGGL(k_hmean, dim3(1024), dim3(256), 0, stream, x, h);
  hipLaunchKernelGGL(k_qk,    dim3(256),  dim3(256), 0, stream, h, wq, wk, q, k);
  hipLaunchKernelGGL(k_adj,   dim3(16),   dim3(256), 0, stream, q, k, sadj, delta_out, cm);
  hipLaunchKernelGGL(k_vsd,   dim3(8),    dim3(256), 0, stream, glin, asrc, adst, vsd16);
  hipLaunchKernelGGL(k_gswz,  dim3(256),  dim3(256), 0, stream, glin, g16s);
  hipLaunchKernelGGL(k_main,  dim3(2048), dim3(512), 0, stream, x, vsd16, cm, g16s, bias, out);
}